// Round 12
// baseline (233.445 us; speedup 1.0000x reference)
//
#include <hip/hip_runtime.h>
#include <hip/hip_bf16.h>

// MultiHeadBatchedMixers, group-sorted two-kernel structure (no atomics):
//   prepack+sort: w1t,w2t,x,b1,b2,w1c,w2c -> bf16 ws; block 0 also builds
//                 order[768] (chains by (e,h)) and order2[384] (bh by (e0,h))
//   Kernel A (grid 1536x256, XCD-chunked, group-ordered): H = GELU(W1c @ X @ W1t^T + B1)
//   Kernel B (grid 1536x512, XCD-chunked, group-ordered, n-split 4): 8 waves, k split
//       across wave halves, LDS combine, plain f32 stores.
// bf16 MFMA 16x16x32, f32 accumulate.
// NOTE (R8/R10 lesson): VGPR+AGPR share one file on gfx950; never set a min-waves
// launch bound on the MFMA kernels (reg cap -> accumulator spill -> WRITE blowup).

namespace {
constexpr int NHEAD = 12, NTOK = 256, HDIM = 64, HIDD = 512, NBATCH = 32, TOPK = 2;
constexpr int NCHAIN = NBATCH * NHEAD * TOPK;  // 768
constexpr int NBH = NBATCH * NHEAD;            // 384
constexpr int NGROUP = 8 * NHEAD;              // 96

// Kernel A LDS: per-wave T1^T [64 e][64 d] bf16, pitch +16B
constexpr int P_T1 = HDIM * 2 + 16;   // 144
constexpr int T1_W = 64 * P_T1;       // 9216
constexpr int SMA_TOTAL = 4 * T1_W;   // 36864
// Kernel B LDS: per-wave T3^T [16 n][64 c] (8 waves); combine aliases [0,16384)
constexpr int P_T3 = HDIM * 2 + 16;   // 144
constexpr int T3_W = 16 * P_T3;       // 2304
constexpr int SMB_TOTAL = 8 * T3_W;   // 18432

// ws layout: [H][w1t][w2t][x][b1][b2][w1c][w2c] bf16, then [order][order2] int
constexpr size_t SZ_H    = (size_t)NCHAIN * HDIM * HIDD;          // 25,165,824
constexpr size_t OFF_H   = 0;
constexpr size_t OFF_W1T = OFF_H + SZ_H;
constexpr size_t SZ_W1T  = (size_t)8 * NHEAD * HIDD * NTOK;       // 12,582,912
constexpr size_t OFF_W2T = OFF_W1T + SZ_W1T;
constexpr size_t SZ_W2T  = (size_t)8 * NHEAD * NTOK * HIDD;
constexpr size_t OFF_X   = OFF_W2T + SZ_W2T;
constexpr size_t SZ_X    = (size_t)NBATCH * NHEAD * HDIM * NTOK;  // 6,291,456
constexpr size_t OFF_B1  = OFF_X + SZ_X;
constexpr size_t SZ_B1   = (size_t)8 * NHEAD * HDIM * HIDD;
constexpr size_t OFF_B2  = OFF_B1 + SZ_B1;
constexpr size_t SZ_B2   = (size_t)8 * NHEAD * HDIM * NTOK;
constexpr size_t OFF_W1C = OFF_B2 + SZ_B2;
constexpr size_t SZ_W1C  = (size_t)8 * NHEAD * HDIM * HDIM;       // 393,216
constexpr size_t OFF_W2C = OFF_W1C + SZ_W1C;
constexpr size_t SZ_W2C  = (size_t)8 * NHEAD * HDIM * HDIM;
constexpr size_t TOTEL   = OFF_W2C + SZ_W2C;                      // shorts
constexpr size_t NEED    = TOTEL * 2 + (NCHAIN + NBH) * 4;
}

typedef float f32x4 __attribute__((ext_vector_type(4)));
typedef short bf16x8 __attribute__((ext_vector_type(8)));
typedef short bf16x4 __attribute__((ext_vector_type(4)));

#define MFMA16(a, b, c) __builtin_amdgcn_mfma_f32_16x16x32_bf16((a), (b), (c), 0, 0, 0)

__device__ __forceinline__ short f2bf(float f) {
  union { float f; unsigned u; } v; v.f = f;
  unsigned r = v.u + 0x7fffu + ((v.u >> 16) & 1u);
  return (short)(r >> 16);
}

__device__ __forceinline__ bf16x8 ld_gfrag(const float* p) {
  float4 a = *(const float4*)p;
  float4 b = *(const float4*)(p + 4);
  bf16x8 r;
  r[0] = f2bf(a.x); r[1] = f2bf(a.y); r[2] = f2bf(a.z); r[3] = f2bf(a.w);
  r[4] = f2bf(b.x); r[5] = f2bf(b.y); r[6] = f2bf(b.z); r[7] = f2bf(b.w);
  return r;
}

__device__ __forceinline__ f32x4 bf4f(bf16x4 v) {
  f32x4 r;
  #pragma unroll
  for (int i = 0; i < 4; ++i) {
    union { unsigned u; float f; } t;
    t.u = ((unsigned)(unsigned short)v[i]) << 16;
    r[i] = t.f;
  }
  return r;
}

__device__ __forceinline__ float gelu_tanh(float x) {
  float u = 0.7978845608028654f * x * (1.0f + 0.044715f * x * x);
  return x / (1.0f + __expf(-2.0f * u));
}

// XCD-chunk swizzle (nwg % 8 == 0): logical sequence contiguous per XCD.
__device__ __forceinline__ int xcd_chunk(int bx, int nwg) {
  return (bx & 7) * (nwg >> 3) + (bx >> 3);
}

// ---------------- Prepack (+ block-0 group sort) ----------------
__global__ __launch_bounds__(256) void prepack_sort_kernel(
    const float* __restrict__ w1t, const float* __restrict__ w2t,
    const float* __restrict__ x, const float* __restrict__ b1,
    const float* __restrict__ b2, const float* __restrict__ w1c,
    const float* __restrict__ w2c, short* __restrict__ wsb,
    const int* __restrict__ eidx, int* __restrict__ order, int* __restrict__ order2) {
  if (blockIdx.x == 0) {
    __shared__ int keys[NCHAIN];
    __shared__ int keys2[NBH];
    __shared__ int cnt[NGROUP + 1];
    __shared__ int cnt2[NGROUP + 1];
    const int t = threadIdx.x;
    for (int i = t; i <= NGROUP; i += 256) { cnt[i] = 0; cnt2[i] = 0; }
    __syncthreads();
    for (int i = t; i < NCHAIN; i += 256) {
      int h = (i >> 1) % NHEAD;
      int key = eidx[i] * NHEAD + h;
      keys[i] = key;
      atomicAdd(&cnt[key + 1], 1);
    }
    for (int i = t; i < NBH; i += 256) {
      int h = i % NHEAD;
      int key = eidx[i * TOPK] * NHEAD + h;
      keys2[i] = key;
      atomicAdd(&cnt2[key + 1], 1);
    }
    __syncthreads();
    if (t == 0) for (int i = 1; i <= NGROUP; ++i) cnt[i] += cnt[i - 1];
    if (t == 1) for (int i = 1; i <= NGROUP; ++i) cnt2[i] += cnt2[i - 1];
    __syncthreads();
    for (int i = t; i < NCHAIN; i += 256) {
      int pos = atomicAdd(&cnt[keys[i]], 1);  // rank within group (order-agnostic downstream)
      order[pos] = i;
    }
    for (int i = t; i < NBH; i += 256) {
      int pos = atomicAdd(&cnt2[keys2[i]], 1);
      order2[pos] = i;
    }
  }

  const size_t C1 = SZ_W1T / 8, C2 = C1 + SZ_W2T / 8, C3 = C2 + SZ_X / 8,
               C4 = C3 + SZ_B1 / 8, C5 = C4 + SZ_B2 / 8, C6 = C5 + SZ_W1C / 8,
               C7 = C6 + SZ_W2C / 8;
  for (size_t i = (size_t)blockIdx.x * blockDim.x + threadIdx.x; i < C7;
       i += (size_t)gridDim.x * blockDim.x) {
    const float* s;
    if (i < C1)      s = w1t + i * 8;
    else if (i < C2) s = w2t + (i - C1) * 8;
    else if (i < C3) s = x   + (i - C2) * 8;
    else if (i < C4) s = b1  + (i - C3) * 8;
    else if (i < C5) s = b2  + (i - C4) * 8;
    else if (i < C6) s = w1c + (i - C5) * 8;
    else             s = w2c + (i - C6) * 8;
    *((bf16x8*)wsb + i) = ld_gfrag(s);
  }
}

// ---------------- Kernel A (64 e per wave) ----------------
// grid = 768*2. logical L (XCD-chunked): sid = L>>1 -> chain = order[sid], eblk = L&1.
template <bool PP>
__global__ __launch_bounds__(256) void mixer_h_kernel(
    const float* __restrict__ x, const int* __restrict__ eidx,
    const float* __restrict__ w1t, const float* __restrict__ w1c, const float* __restrict__ b1,
    const short* __restrict__ wsb, const int* __restrict__ order, short* __restrict__ hws) {
  __shared__ __align__(16) char smem[SMA_TOTAL];
  const int L = xcd_chunk(blockIdx.x, NCHAIN * 2);
  const int sid = L >> 1, eblk = L & 1;
  const int bhk = PP ? order[sid] : sid;
  const int h = (bhk >> 1) % NHEAD;
  const int tid = threadIdx.x, w = tid >> 6, lane = tid & 63, lr = lane & 15, lg = lane >> 4;

  const int e = eidx[bhk];
  const size_t eh = (size_t)e * NHEAD + h;
  short* H = hws + (size_t)bhk * HDIM * HIDD;

  const int e0 = eblk * 256 + w * 64;

  // MFMA1: T1[d][e] = sum_n X[d,n]*W1t[e,n];  A=X (m=d), B=W1t (n=e), k=n
  f32x4 acc1[4][4];  // [et][dt]
  #pragma unroll
  for (int et = 0; et < 4; ++et)
    #pragma unroll
    for (int dt = 0; dt < 4; ++dt) acc1[et][dt] = (f32x4){0.f, 0.f, 0.f, 0.f};
  #pragma unroll
  for (int ks = 0; ks < 8; ++ks) {
    bf16x8 wfr[4];
    #pragma unroll
    for (int et = 0; et < 4; ++et) {
      if (PP) wfr[et] = *(const bf16x8*)(wsb + OFF_W1T + eh * HIDD * NTOK +
                                         (size_t)(e0 + et * 16 + lr) * NTOK + ks * 32 + lg * 8);
      else    wfr[et] = ld_gfrag(w1t + eh * HIDD * NTOK +
                                 (size_t)(e0 + et * 16 + lr) * NTOK + ks * 32 + lg * 8);
    }
    #pragma unroll
    for (int dt = 0; dt < 4; ++dt) {
      bf16x8 xfr;
      if (PP) xfr = *(const bf16x8*)(wsb + OFF_X + (size_t)(bhk >> 1) * HDIM * NTOK +
                                     (size_t)(dt * 16 + lr) * NTOK + ks * 32 + lg * 8);
      else    xfr = ld_gfrag(x + (size_t)(bhk >> 1) * HDIM * NTOK +
                             (size_t)(dt * 16 + lr) * NTOK + ks * 32 + lg * 8);
      #pragma unroll
      for (int et = 0; et < 4; ++et) acc1[et][dt] = MFMA16(xfr, wfr[et], acc1[et][dt]);
    }
  }

  // relayout T1^T via wave-private LDS (col=e=lr, row=d=dt*16+lg*4+i) -> [e][d]
  char* t1 = smem + w * T1_W;
  #pragma unroll
  for (int et = 0; et < 4; ++et)
    #pragma unroll
    for (int dt = 0; dt < 4; ++dt) {
      bf16x4 p;
      #pragma unroll
      for (int i = 0; i < 4; ++i) p[i] = f2bf(acc1[et][dt][i]);
      *(bf16x4*)(t1 + (et * 16 + lr) * P_T1 + (dt * 16 + lg * 4) * 2) = p;
    }

  // MFMA2: T2^T[e][c] = sum_d T1^T[e,d]*W1c[c,d] + B1;  D: col=c=lr, row=e=lg*4+i
  f32x4 acc2[4][4];  // [et][ct]
  #pragma unroll
  for (int et = 0; et < 4; ++et)
    #pragma unroll
    for (int ct = 0; ct < 4; ++ct) {
      if (PP) {
        bf16x4 bb = *(const bf16x4*)(wsb + OFF_B1 + eh * HDIM * HIDD +
                                     (size_t)(ct * 16 + lr) * HIDD + e0 + et * 16 + lg * 4);
        acc2[et][ct] = bf4f(bb);
      } else {
        acc2[et][ct] = *(const f32x4*)(b1 + eh * HDIM * HIDD +
                                       (size_t)(ct * 16 + lr) * HIDD + e0 + et * 16 + lg * 4);
      }
    }
  #pragma unroll
  for (int ks = 0; ks < 2; ++ks) {
    bf16x8 a[4];
    #pragma unroll
    for (int et = 0; et < 4; ++et)
      a[et] = *(const bf16x8*)(t1 + (et * 16 + lr) * P_T1 + (ks * 32 + lg * 8) * 2);
    #pragma unroll
    for (int ct = 0; ct < 4; ++ct) {
      bf16x8 bfr;
      if (PP) bfr = *(const bf16x8*)(wsb + OFF_W1C + eh * HDIM * HDIM +
                                     (size_t)(ct * 16 + lr) * HDIM + ks * 32 + lg * 8);
      else    bfr = ld_gfrag(w1c + eh * HDIM * HDIM +
                             (size_t)(ct * 16 + lr) * HDIM + ks * 32 + lg * 8);
      #pragma unroll
      for (int et = 0; et < 4; ++et) acc2[et][ct] = MFMA16(a[et], bfr, acc2[et][ct]);
    }
  }

  // GELU + store H[c][e] (col=c=lr, row=e=lg*4+i)
  #pragma unroll
  for (int et = 0; et < 4; ++et)
    #pragma unroll
    for (int ct = 0; ct < 4; ++ct) {
      bf16x4 g;
      #pragma unroll
      for (int i = 0; i < 4; ++i) g[i] = f2bf(gelu_tanh(acc2[et][ct][i]));
      *(bf16x4*)(H + (size_t)(ct * 16 + lr) * HIDD + e0 + et * 16 + lg * 4) = g;
    }
}

// ---------------- Kernel B (n-split 4, 8 waves, k split across wave halves) ----------------
// grid = 1536 x 512. logical L: sid = L>>2 -> bh = order2[sid], nq = L&3.
// Wave w: kk = w>>2, n rows [nq*64 + (w&3)*16, +16). k=1 waves publish weighted
// partials via LDS (aliases dead t3), k=0 waves combine + plain f32 stores.
template <bool PP>
__global__ __launch_bounds__(512) void mixer_out_kernel(
    const int* __restrict__ eidx, const float* __restrict__ ewt,
    const float* __restrict__ w2t, const float* __restrict__ w2c, const float* __restrict__ b2,
    const short* __restrict__ wsb, const int* __restrict__ order2,
    const short* __restrict__ hws, float* __restrict__ out) {
  __shared__ __align__(16) char smem[SMB_TOTAL];
  const int L = xcd_chunk(blockIdx.x, NBH * 4);
  const int sid = L >> 2, nq = L & 3;
  const int bh = PP ? order2[sid] : sid;
  const int h = bh % NHEAD;
  const int tid = threadIdx.x, w = tid >> 6, lane = tid & 63, lr = lane & 15, lg = lane >> 4;
  const int kk = w >> 2, wq = w & 3;
  const int nb = nq * 64 + wq * 16;
  char* t3 = smem + w * T3_W;
  float* OUT = out + (size_t)bh * HDIM * NTOK;

  const int e = eidx[bh * TOPK + kk];
  const float wk = ewt[bh * TOPK + kk];
  const size_t eh = (size_t)e * NHEAD + h;
  const short* Hk = hws + (size_t)(bh * TOPK + kk) * HDIM * HIDD;

  // MFMA3: T3[c][n] = sum_e H[c,e]*W2t[n,e];  A=H (m=c), B=W2t (n=n), k=e
  f32x4 acc3[4];
  #pragma unroll
  for (int ct = 0; ct < 4; ++ct) acc3[ct] = (f32x4){0.f, 0.f, 0.f, 0.f};
  #pragma unroll 4
  for (int ks = 0; ks < 16; ++ks) {
    bf16x8 a[4];
    #pragma unroll
    for (int ct = 0; ct < 4; ++ct)
      a[ct] = *(const bf16x8*)(Hk + (size_t)(ct * 16 + lr) * HIDD + ks * 32 + lg * 8);
    bf16x8 bfr;
    if (PP) bfr = *(const bf16x8*)(wsb + OFF_W2T + eh * NTOK * HIDD +
                                   (size_t)(nb + lr) * HIDD + ks * 32 + lg * 8);
    else    bfr = ld_gfrag(w2t + eh * NTOK * HIDD +
                           (size_t)(nb + lr) * HIDD + ks * 32 + lg * 8);
    #pragma unroll
    for (int ct = 0; ct < 4; ++ct) acc3[ct] = MFMA16(a[ct], bfr, acc3[ct]);
  }

  // relayout T3^T via wave-private LDS (col=n=lr, row=c=ct*16+lg*4+i) -> [n][c]
  #pragma unroll
  for (int ct = 0; ct < 4; ++ct) {
    bf16x4 p;
    #pragma unroll
    for (int i = 0; i < 4; ++i) p[i] = f2bf(acc3[ct][i]);
    *(bf16x4*)(t3 + lr * P_T3 + (ct * 16 + lg * 4) * 2) = p;
  }

  // MFMA4: OUT^T[n][co] = sum_c T3^T[n,c]*W2c[co,c]
  f32x4 acc4[4];
  #pragma unroll
  for (int cot = 0; cot < 4; ++cot) acc4[cot] = (f32x4){0.f, 0.f, 0.f, 0.f};
  #pragma unroll
  for (int ks = 0; ks < 2; ++ks) {
    bf16x8 a = *(const bf16x8*)(t3 + lr * P_T3 + (ks * 32 + lg * 8) * 2);
    #pragma unroll
    for (int cot = 0; cot < 4; ++cot) {
      bf16x8 bfr;
      if (PP) bfr = *(const bf16x8*)(wsb + OFF_W2C + eh * HDIM * HDIM +
                                     (size_t)(cot * 16 + lr) * HDIM + ks * 32 + lg * 8);
      else    bfr = ld_gfrag(w2c + eh * HDIM * HDIM +
                             (size_t)(cot * 16 + lr) * HDIM + ks * 32 + lg * 8);
      acc4[cot] = MFMA16(a, bfr, acc4[cot]);
    }
  }

  // weighted partial in place: acc4 = wk*(acc4 + B2)  (col=co=lr, row=n=lg*4+i)
  #pragma unroll
  for (int cot = 0; cot < 4; ++cot) {
    const int co = cot * 16 + lr;
    const int n0 = nb + lg * 4;
    f32x4 bb;
    if (PP) bb = bf4f(*(const bf16x4*)(wsb + OFF_B2 + eh * HDIM * NTOK + (size_t)co * NTOK + n0));
    else    bb = *(const f32x4*)(b2 + eh * HDIM * NTOK + (size_t)co * NTOK + n0);
    #pragma unroll
    for (int i = 0; i < 4; ++i) acc4[cot][i] = wk * (acc4[cot][i] + bb[i]);
  }

  __syncthreads();  // all waves done reading their t3 (comb aliases t3 region)

  // k=1 waves publish partials: comb[wq] = [16 n][64 co] f32 at offset wq*4096
  if (kk == 1) {
    float* comb = (float*)(smem + wq * 4096);
    #pragma unroll
    for (int cot = 0; cot < 4; ++cot) {
      const int co = cot * 16 + lr;
      #pragma unroll
      for (int i = 0; i < 4; ++i)
        comb[(lg * 4 + i) * 64 + co] = acc4[cot][i];
    }
  }
  __syncthreads();

  // k=0 waves combine + store (each (co,n) written exactly once across the grid)
  if (kk == 0) {
    const float* comb = (const float*)(smem + wq * 4096);
    #pragma unroll
    for (int cot = 0; cot < 4; ++cot) {
      const int co = cot * 16 + lr;
      const int n0 = nb + lg * 4;
      f32x4 v;
      #pragma unroll
      for (int i = 0; i < 4; ++i)
        v[i] = acc4[cot][i] + comb[(lg * 4 + i) * 64 + co];
      *(f32x4*)(OUT + (size_t)co * NTOK + n0) = v;
    }
  }
}

extern "C" void kernel_launch(void* const* d_in, const int* in_sizes, int n_in,
                              void* d_out, int out_size, void* d_ws, size_t ws_size,
                              hipStream_t stream) {
  const float* x   = (const float*)d_in[0];
  const int*   ei  = (const int*)d_in[1];
  const float* ew  = (const float*)d_in[2];
  const float* w1t = (const float*)d_in[3];
  const float* w1c = (const float*)d_in[4];
  const float* b1  = (const float*)d_in[5];
  const float* w2t = (const float*)d_in[6];
  const float* w2c = (const float*)d_in[7];
  const float* b2  = (const float*)d_in[8];
  float* out = (float*)d_out;
  short* wsb = (short*)d_ws;
  short* hws = wsb + OFF_H;
  int* order  = (int*)(wsb + TOTEL);
  int* order2 = order + NCHAIN;

  if (ws_size >= NEED) {
    prepack_sort_kernel<<<dim3(2048), dim3(256), 0, stream>>>(
        w1t, w2t, x, b1, b2, w1c, w2c, wsb + OFF_W1T, ei, order, order2);
    mixer_h_kernel<true><<<dim3(NCHAIN * 2), dim3(256), 0, stream>>>(
        x, ei, w1t, w1c, b1, wsb, order, hws);
    mixer_out_kernel<true><<<dim3(NBH * 4), dim3(512), 0, stream>>>(
        ei, ew, w2t, w2c, b2, wsb, order2, hws, out);
  } else {
    mixer_h_kernel<false><<<dim3(NCHAIN * 2), dim3(256), 0, stream>>>(
        x, ei, w1t, w1c, b1, wsb, order, hws);
    mixer_out_kernel<false><<<dim3(NBH * 4), dim3(512), 0, stream>>>(
        ei, ew, w2t, w2c, b2, wsb, order2, hws, out);
  }
}

// Round 13
// 194.044 us; speedup vs baseline: 1.2031x; 1.2031x over previous
//
#include <hip/hip_runtime.h>
#include <hip/hip_bf16.h>

// MultiHeadBatchedMixers, group-sorted two-kernel structure (no atomics):
//   prepack1: w1t,x,b1,w1c -> bf16 ws; block 0 builds order[768]/order2[384]
//   Kernel A (grid 2048x256): blocks with (bx&31)<24 run mixer-A (XCD-chunked,
//       group-ordered, 64 e/wave); blocks with (bx&31)>=24 convert w2t,b2,w2c
//       (overlapped prepack of B-data under A's latency bubbles)
//   Kernel B (grid 1536x256, XCD-chunked, group-ordered): 4 waves = 2 k x 2 wq,
//       nt=2 per wave (R11 intensity), LDS combine, plain f32 stores.
// bf16 MFMA 16x16x32, f32 accumulate.
// NOTE (R8/R10): VGPR+AGPR share one file on gfx950; never min-waves-bound the
// MFMA kernels (reg cap -> accumulator spill -> WRITE blowup).
// NOTE (R12): B's cost tracks TOTAL load instructions; keep nt>=2 (>=1.33 MFMA/load)
// and per-bh H-read instruction count fixed when re-gridding.

namespace {
constexpr int NHEAD = 12, NTOK = 256, HDIM = 64, HIDD = 512, NBATCH = 32, TOPK = 2;
constexpr int NCHAIN = NBATCH * NHEAD * TOPK;  // 768
constexpr int NBH = NBATCH * NHEAD;            // 384
constexpr int NGROUP = 8 * NHEAD;              // 96

// Kernel A LDS: per-wave T1^T [64 e][64 d] bf16, pitch +16B
constexpr int P_T1 = HDIM * 2 + 16;   // 144
constexpr int T1_W = 64 * P_T1;       // 9216
constexpr int SMA_TOTAL = 4 * T1_W;   // 36864
// Kernel B LDS: per-wave T3^T [32 n][64 c] (4 waves); combine aliases [0,16384)
constexpr int P_T3 = HDIM * 2 + 16;   // 144
constexpr int T3_W = 32 * P_T3;       // 4608
constexpr int SMB_TOTAL = 4 * T3_W;   // 18432

// ws layout: [H][w1t][w2t][x][b1][b2][w1c][w2c] bf16, then [order][order2] int
constexpr size_t SZ_H    = (size_t)NCHAIN * HDIM * HIDD;          // 25,165,824
constexpr size_t OFF_H   = 0;
constexpr size_t OFF_W1T = OFF_H + SZ_H;
constexpr size_t SZ_W1T  = (size_t)8 * NHEAD * HIDD * NTOK;       // 12,582,912
constexpr size_t OFF_W2T = OFF_W1T + SZ_W1T;
constexpr size_t SZ_W2T  = (size_t)8 * NHEAD * NTOK * HIDD;
constexpr size_t OFF_X   = OFF_W2T + SZ_W2T;
constexpr size_t SZ_X    = (size_t)NBATCH * NHEAD * HDIM * NTOK;  // 6,291,456
constexpr size_t OFF_B1  = OFF_X + SZ_X;
constexpr size_t SZ_B1   = (size_t)8 * NHEAD * HDIM * HIDD;
constexpr size_t OFF_B2  = OFF_B1 + SZ_B1;
constexpr size_t SZ_B2   = (size_t)8 * NHEAD * HDIM * NTOK;
constexpr size_t OFF_W1C = OFF_B2 + SZ_B2;
constexpr size_t SZ_W1C  = (size_t)8 * NHEAD * HDIM * HDIM;       // 393,216
constexpr size_t OFF_W2C = OFF_W1C + SZ_W1C;
constexpr size_t SZ_W2C  = (size_t)8 * NHEAD * HDIM * HDIM;
constexpr size_t TOTEL   = OFF_W2C + SZ_W2C;                      // shorts
constexpr size_t NEED    = TOTEL * 2 + (NCHAIN + NBH) * 4;
}

typedef float f32x4 __attribute__((ext_vector_type(4)));
typedef short bf16x8 __attribute__((ext_vector_type(8)));
typedef short bf16x4 __attribute__((ext_vector_type(4)));

#define MFMA16(a, b, c) __builtin_amdgcn_mfma_f32_16x16x32_bf16((a), (b), (c), 0, 0, 0)

__device__ __forceinline__ short f2bf(float f) {
  union { float f; unsigned u; } v; v.f = f;
  unsigned r = v.u + 0x7fffu + ((v.u >> 16) & 1u);
  return (short)(r >> 16);
}

__device__ __forceinline__ bf16x8 ld_gfrag(const float* p) {
  float4 a = *(const float4*)p;
  float4 b = *(const float4*)(p + 4);
  bf16x8 r;
  r[0] = f2bf(a.x); r[1] = f2bf(a.y); r[2] = f2bf(a.z); r[3] = f2bf(a.w);
  r[4] = f2bf(b.x); r[5] = f2bf(b.y); r[6] = f2bf(b.z); r[7] = f2bf(b.w);
  return r;
}

__device__ __forceinline__ f32x4 bf4f(bf16x4 v) {
  f32x4 r;
  #pragma unroll
  for (int i = 0; i < 4; ++i) {
    union { unsigned u; float f; } t;
    t.u = ((unsigned)(unsigned short)v[i]) << 16;
    r[i] = t.f;
  }
  return r;
}

__device__ __forceinline__ float gelu_tanh(float x) {
  float u = 0.7978845608028654f * x * (1.0f + 0.044715f * x * x);
  return x / (1.0f + __expf(-2.0f * u));
}

// XCD-chunk swizzle (nwg % 8 == 0): logical sequence contiguous per XCD.
__device__ __forceinline__ int xcd_chunk(int bx, int nwg) {
  return (bx & 7) * (nwg >> 3) + (bx >> 3);
}

// ---------------- Prepack1: A-data f32 -> bf16 (+ block-0 group sort) ----------------
__global__ __launch_bounds__(256) void prepack_sortA_kernel(
    const float* __restrict__ w1t, const float* __restrict__ x,
    const float* __restrict__ b1, const float* __restrict__ w1c,
    short* __restrict__ wsb,
    const int* __restrict__ eidx, int* __restrict__ order, int* __restrict__ order2) {
  if (blockIdx.x == 0) {
    __shared__ int keys[NCHAIN];
    __shared__ int keys2[NBH];
    __shared__ int cnt[NGROUP + 1];
    __shared__ int cnt2[NGROUP + 1];
    const int t = threadIdx.x;
    for (int i = t; i <= NGROUP; i += 256) { cnt[i] = 0; cnt2[i] = 0; }
    __syncthreads();
    for (int i = t; i < NCHAIN; i += 256) {
      int h = (i >> 1) % NHEAD;
      int key = eidx[i] * NHEAD + h;
      keys[i] = key;
      atomicAdd(&cnt[key + 1], 1);
    }
    for (int i = t; i < NBH; i += 256) {
      int h = i % NHEAD;
      int key = eidx[i * TOPK] * NHEAD + h;
      keys2[i] = key;
      atomicAdd(&cnt2[key + 1], 1);
    }
    __syncthreads();
    if (t == 0) for (int i = 1; i <= NGROUP; ++i) cnt[i] += cnt[i - 1];
    if (t == 1) for (int i = 1; i <= NGROUP; ++i) cnt2[i] += cnt2[i - 1];
    __syncthreads();
    for (int i = t; i < NCHAIN; i += 256) {
      int pos = atomicAdd(&cnt[keys[i]], 1);  // rank within group (order-agnostic downstream)
      order[pos] = i;
    }
    for (int i = t; i < NBH; i += 256) {
      int pos = atomicAdd(&cnt2[keys2[i]], 1);
      order2[pos] = i;
    }
  }

  // segments: w1t, x, b1, w1c (vec8 units)
  const size_t d1 = SZ_W1T / 8, d2 = d1 + SZ_X / 8, d3 = d2 + SZ_B1 / 8,
               d4 = d3 + SZ_W1C / 8;
  for (size_t i = (size_t)blockIdx.x * blockDim.x + threadIdx.x; i < d4;
       i += (size_t)gridDim.x * blockDim.x) {
    const float* s; size_t doff;
    if (i < d1)      { s = w1t + i * 8;        doff = OFF_W1T + i * 8; }
    else if (i < d2) { s = x + (i - d1) * 8;   doff = OFF_X + (i - d1) * 8; }
    else if (i < d3) { s = b1 + (i - d2) * 8;  doff = OFF_B1 + (i - d2) * 8; }
    else             { s = w1c + (i - d3) * 8; doff = OFF_W1C + (i - d3) * 8; }
    *(bf16x8*)(wsb + doff) = ld_gfrag(s);
  }
}

// ---------------- Kernel A (64 e per wave) + embedded B-data conversion ----------------
// grid = 2048. (bx&31)>=24 -> conversion block (cidx over 512 blocks), spread across
// all XCDs. Else A-block: aidx = (bx>>5)*24 + (bx&31); aidx%8 == bx%8 so the XCD
// chunk swizzle is preserved. L = xcd_chunk(aidx,1536): sid=L>>1 chain, eblk=L&1.
template <bool PP>
__global__ __launch_bounds__(256) void mixer_h_cvt_kernel(
    const float* __restrict__ x, const int* __restrict__ eidx,
    const float* __restrict__ w1t, const float* __restrict__ w1c, const float* __restrict__ b1,
    const float* __restrict__ w2t, const float* __restrict__ b2, const float* __restrict__ w2c,
    short* __restrict__ wsb, const int* __restrict__ order, short* __restrict__ hws) {
  __shared__ __align__(16) char smem[SMA_TOTAL];
  const int bx = blockIdx.x;
  const int sub = bx & 31;

  if (sub >= 24) {
    // ---- conversion block: w2t, b2, w2c -> bf16 ws (only meaningful when PP) ----
    if (!PP) return;
    const int cidx = (bx >> 5) * 8 + (sub - 24);           // [0,512)
    const size_t c1 = SZ_W2T / 8, c2 = c1 + SZ_B2 / 8, c3 = c2 + SZ_W2C / 8;
    for (size_t i = (size_t)cidx * blockDim.x + threadIdx.x; i < c3;
         i += (size_t)512 * blockDim.x) {
      const float* s; size_t doff;
      if (i < c1)      { s = w2t + i * 8;        doff = OFF_W2T + i * 8; }
      else if (i < c2) { s = b2 + (i - c1) * 8;  doff = OFF_B2 + (i - c1) * 8; }
      else             { s = w2c + (i - c2) * 8; doff = OFF_W2C + (i - c2) * 8; }
      *(bf16x8*)(wsb + doff) = ld_gfrag(s);
    }
    return;
  }

  const int aidx = (bx >> 5) * 24 + sub;                   // [0,1536)
  const int L = xcd_chunk(aidx, NCHAIN * 2);
  const int sid = L >> 1, eblk = L & 1;
  const int bhk = PP ? order[sid] : sid;
  const int h = (bhk >> 1) % NHEAD;
  const int tid = threadIdx.x, w = tid >> 6, lane = tid & 63, lr = lane & 15, lg = lane >> 4;

  const int e = eidx[bhk];
  const size_t eh = (size_t)e * NHEAD + h;
  short* H = hws + (size_t)bhk * HDIM * HIDD;

  const int e0 = eblk * 256 + w * 64;

  // MFMA1: T1[d][e] = sum_n X[d,n]*W1t[e,n];  A=X (m=d), B=W1t (n=e), k=n
  f32x4 acc1[4][4];  // [et][dt]
  #pragma unroll
  for (int et = 0; et < 4; ++et)
    #pragma unroll
    for (int dt = 0; dt < 4; ++dt) acc1[et][dt] = (f32x4){0.f, 0.f, 0.f, 0.f};
  #pragma unroll
  for (int ks = 0; ks < 8; ++ks) {
    bf16x8 wfr[4];
    #pragma unroll
    for (int et = 0; et < 4; ++et) {
      if (PP) wfr[et] = *(const bf16x8*)(wsb + OFF_W1T + eh * HIDD * NTOK +
                                         (size_t)(e0 + et * 16 + lr) * NTOK + ks * 32 + lg * 8);
      else    wfr[et] = ld_gfrag(w1t + eh * HIDD * NTOK +
                                 (size_t)(e0 + et * 16 + lr) * NTOK + ks * 32 + lg * 8);
    }
    #pragma unroll
    for (int dt = 0; dt < 4; ++dt) {
      bf16x8 xfr;
      if (PP) xfr = *(const bf16x8*)(wsb + OFF_X + (size_t)(bhk >> 1) * HDIM * NTOK +
                                     (size_t)(dt * 16 + lr) * NTOK + ks * 32 + lg * 8);
      else    xfr = ld_gfrag(x + (size_t)(bhk >> 1) * HDIM * NTOK +
                             (size_t)(dt * 16 + lr) * NTOK + ks * 32 + lg * 8);
      #pragma unroll
      for (int et = 0; et < 4; ++et) acc1[et][dt] = MFMA16(xfr, wfr[et], acc1[et][dt]);
    }
  }

  // relayout T1^T via wave-private LDS (col=e=lr, row=d=dt*16+lg*4+i) -> [e][d]
  char* t1 = smem + w * T1_W;
  #pragma unroll
  for (int et = 0; et < 4; ++et)
    #pragma unroll
    for (int dt = 0; dt < 4; ++dt) {
      bf16x4 p;
      #pragma unroll
      for (int i = 0; i < 4; ++i) p[i] = f2bf(acc1[et][dt][i]);
      *(bf16x4*)(t1 + (et * 16 + lr) * P_T1 + (dt * 16 + lg * 4) * 2) = p;
    }

  // MFMA2: T2^T[e][c] = sum_d T1^T[e,d]*W1c[c,d] + B1;  D: col=c=lr, row=e=lg*4+i
  f32x4 acc2[4][4];  // [et][ct]
  #pragma unroll
  for (int et = 0; et < 4; ++et)
    #pragma unroll
    for (int ct = 0; ct < 4; ++ct) {
      if (PP) {
        bf16x4 bb = *(const bf16x4*)(wsb + OFF_B1 + eh * HDIM * HIDD +
                                     (size_t)(ct * 16 + lr) * HIDD + e0 + et * 16 + lg * 4);
        acc2[et][ct] = bf4f(bb);
      } else {
        acc2[et][ct] = *(const f32x4*)(b1 + eh * HDIM * HIDD +
                                       (size_t)(ct * 16 + lr) * HIDD + e0 + et * 16 + lg * 4);
      }
    }
  #pragma unroll
  for (int ks = 0; ks < 2; ++ks) {
    bf16x8 a[4];
    #pragma unroll
    for (int et = 0; et < 4; ++et)
      a[et] = *(const bf16x8*)(t1 + (et * 16 + lr) * P_T1 + (ks * 32 + lg * 8) * 2);
    #pragma unroll
    for (int ct = 0; ct < 4; ++ct) {
      bf16x8 bfr;
      if (PP) bfr = *(const bf16x8*)(wsb + OFF_W1C + eh * HDIM * HDIM +
                                     (size_t)(ct * 16 + lr) * HDIM + ks * 32 + lg * 8);
      else    bfr = ld_gfrag(w1c + eh * HDIM * HDIM +
                             (size_t)(ct * 16 + lr) * HDIM + ks * 32 + lg * 8);
      #pragma unroll
      for (int et = 0; et < 4; ++et) acc2[et][ct] = MFMA16(a[et], bfr, acc2[et][ct]);
    }
  }

  // GELU + store H[c][e] (col=c=lr, row=e=lg*4+i)
  #pragma unroll
  for (int et = 0; et < 4; ++et)
    #pragma unroll
    for (int ct = 0; ct < 4; ++ct) {
      bf16x4 g;
      #pragma unroll
      for (int i = 0; i < 4; ++i) g[i] = f2bf(gelu_tanh(acc2[et][ct][i]));
      *(bf16x4*)(H + (size_t)(ct * 16 + lr) * HIDD + e0 + et * 16 + lg * 4) = g;
    }
}

// ---------------- Kernel B (grid 1536 x 256: 4 waves = 2 k x 2 wq, nt=2) ----------------
// L = xcd_chunk(bx,1536): sid = L>>2 -> bh = order2[sid], nq = L&3.
// Wave w: kk = w>>1, wq = w&1; n rows [nq*64 + wq*32, +32). k=1 waves publish
// weighted partials via LDS (aliases dead t3), k=0 waves combine + f32 stores.
template <bool PP>
__global__ __launch_bounds__(256) void mixer_out_kernel(
    const int* __restrict__ eidx, const float* __restrict__ ewt,
    const float* __restrict__ w2t, const float* __restrict__ w2c, const float* __restrict__ b2,
    const short* __restrict__ wsb, const int* __restrict__ order2,
    const short* __restrict__ hws, float* __restrict__ out) {
  __shared__ __align__(16) char smem[SMB_TOTAL];
  const int L = xcd_chunk(blockIdx.x, NBH * 4);
  const int sid = L >> 2, nq = L & 3;
  const int bh = PP ? order2[sid] : sid;
  const int h = bh % NHEAD;
  const int tid = threadIdx.x, w = tid >> 6, lane = tid & 63, lr = lane & 15, lg = lane >> 4;
  const int kk = w >> 1, wq = w & 1;
  const int nb = nq * 64 + wq * 32;
  char* t3 = smem + w * T3_W;
  float* OUT = out + (size_t)bh * HDIM * NTOK;

  const int e = eidx[bh * TOPK + kk];
  const float wk = ewt[bh * TOPK + kk];
  const size_t eh = (size_t)e * NHEAD + h;
  const short* Hk = hws + (size_t)(bh * TOPK + kk) * HDIM * HIDD;

  // MFMA3: T3[c][n] = sum_e H[c,e]*W2t[n,e];  A=H (m=c), B=W2t (n=n), k=e
  f32x4 acc3[4][2];
  #pragma unroll
  for (int ct = 0; ct < 4; ++ct)
    #pragma unroll
    for (int nt = 0; nt < 2; ++nt) acc3[ct][nt] = (f32x4){0.f, 0.f, 0.f, 0.f};
  #pragma unroll 4
  for (int ks = 0; ks < 16; ++ks) {
    bf16x8 a[4];
    #pragma unroll
    for (int ct = 0; ct < 4; ++ct)
      a[ct] = *(const bf16x8*)(Hk + (size_t)(ct * 16 + lr) * HIDD + ks * 32 + lg * 8);
    #pragma unroll
    for (int nt = 0; nt < 2; ++nt) {
      bf16x8 bfr;
      if (PP) bfr = *(const bf16x8*)(wsb + OFF_W2T + eh * NTOK * HIDD +
                                     (size_t)(nb + nt * 16 + lr) * HIDD + ks * 32 + lg * 8);
      else    bfr = ld_gfrag(w2t + eh * NTOK * HIDD +
                             (size_t)(nb + nt * 16 + lr) * HIDD + ks * 32 + lg * 8);
      #pragma unroll
      for (int ct = 0; ct < 4; ++ct) acc3[ct][nt] = MFMA16(a[ct], bfr, acc3[ct][nt]);
    }
  }

  // relayout T3^T via wave-private LDS (col=n=lr, row=c=ct*16+lg*4+i) -> [n][c]
  #pragma unroll
  for (int ct = 0; ct < 4; ++ct)
    #pragma unroll
    for (int nt = 0; nt < 2; ++nt) {
      bf16x4 p;
      #pragma unroll
      for (int i = 0; i < 4; ++i) p[i] = f2bf(acc3[ct][nt][i]);
      *(bf16x4*)(t3 + (nt * 16 + lr) * P_T3 + (ct * 16 + lg * 4) * 2) = p;
    }

  // MFMA4: OUT^T[n][co] = sum_c T3^T[n,c]*W2c[co,c]
  f32x4 acc4[2][4];
  #pragma unroll
  for (int nt = 0; nt < 2; ++nt)
    #pragma unroll
    for (int ct = 0; ct < 4; ++ct) acc4[nt][ct] = (f32x4){0.f, 0.f, 0.f, 0.f};
  #pragma unroll
  for (int ks = 0; ks < 2; ++ks) {
    bf16x8 a[2];
    #pragma unroll
    for (int nt = 0; nt < 2; ++nt)
      a[nt] = *(const bf16x8*)(t3 + (nt * 16 + lr) * P_T3 + (ks * 32 + lg * 8) * 2);
    #pragma unroll
    for (int ct = 0; ct < 4; ++ct) {
      bf16x8 bfr;
      if (PP) bfr = *(const bf16x8*)(wsb + OFF_W2C + eh * HDIM * HDIM +
                                     (size_t)(ct * 16 + lr) * HDIM + ks * 32 + lg * 8);
      else    bfr = ld_gfrag(w2c + eh * HDIM * HDIM +
                             (size_t)(ct * 16 + lr) * HDIM + ks * 32 + lg * 8);
      #pragma unroll
      for (int nt = 0; nt < 2; ++nt) acc4[nt][ct] = MFMA16(a[nt], bfr, acc4[nt][ct]);
    }
  }

  // weighted partial in place: acc4 = wk*(acc4 + B2)  (col=co=lr, row=n=lg*4+i)
  #pragma unroll
  for (int nt = 0; nt < 2; ++nt)
    #pragma unroll
    for (int cot = 0; cot < 4; ++cot) {
      const int co = cot * 16 + lr;
      const int n0 = nb + nt * 16 + lg * 4;
      f32x4 bb;
      if (PP) bb = bf4f(*(const bf16x4*)(wsb + OFF_B2 + eh * HDIM * NTOK + (size_t)co * NTOK + n0));
      else    bb = *(const f32x4*)(b2 + eh * HDIM * NTOK + (size_t)co * NTOK + n0);
      #pragma unroll
      for (int i = 0; i < 4; ++i) acc4[nt][cot][i] = wk * (acc4[nt][cot][i] + bb[i]);
    }

  __syncthreads();  // all waves done reading their t3 (comb aliases t3 region)

  // k=1 waves publish partials: comb[wq] = [32 n][64 co] f32 at offset wq*8192
  if (kk == 1) {
    float* comb = (float*)(smem + wq * 8192);
    #pragma unroll
    for (int nt = 0; nt < 2; ++nt)
      #pragma unroll
      for (int cot = 0; cot < 4; ++cot) {
        const int co = cot * 16 + lr;
        #pragma unroll
        for (int i = 0; i < 4; ++i)
          comb[(nt * 16 + lg * 4 + i) * 64 + co] = acc4[nt][cot][i];
      }
  }
  __syncthreads();

  // k=0 waves combine + store (each (co,n) written exactly once across the grid)
  if (kk == 0) {
    const float* comb = (const float*)(smem + wq * 8192);
    #pragma unroll
    for (int nt = 0; nt < 2; ++nt)
      #pragma unroll
      for (int cot = 0; cot < 4; ++cot) {
        const int co = cot * 16 + lr;
        const int n0 = nb + nt * 16 + lg * 4;
        f32x4 v;
        #pragma unroll
        for (int i = 0; i < 4; ++i)
          v[i] = acc4[nt][cot][i] + comb[(nt * 16 + lg * 4 + i) * 64 + co];
        *(f32x4*)(OUT + (size_t)co * NTOK + n0) = v;
      }
  }
}

extern "C" void kernel_launch(void* const* d_in, const int* in_sizes, int n_in,
                              void* d_out, int out_size, void* d_ws, size_t ws_size,
                              hipStream_t stream) {
  const float* x   = (const float*)d_in[0];
  const int*   ei  = (const int*)d_in[1];
  const float* ew  = (const float*)d_in[2];
  const float* w1t = (const float*)d_in[3];
  const float* w1c = (const float*)d_in[4];
  const float* b1  = (const float*)d_in[5];
  const float* w2t = (const float*)d_in[6];
  const float* w2c = (const float*)d_in[7];
  const float* b2  = (const float*)d_in[8];
  float* out = (float*)d_out;
  short* wsb = (short*)d_ws;
  short* hws = wsb + OFF_H;
  int* order  = (int*)(wsb + TOTEL);
  int* order2 = order + NCHAIN;

  if (ws_size >= NEED) {
    prepack_sortA_kernel<<<dim3(1024), dim3(256), 0, stream>>>(
        w1t, x, b1, w1c, wsb, ei, order, order2);
    mixer_h_cvt_kernel<true><<<dim3(2048), dim3(256), 0, stream>>>(
        x, ei, w1t, w1c, b1, w2t, b2, w2c, wsb, order, hws);
    mixer_out_kernel<true><<<dim3(NBH * 4), dim3(256), 0, stream>>>(
        ei, ew, w2t, w2c, b2, wsb, order2, hws, out);
  } else {
    mixer_h_cvt_kernel<false><<<dim3(2048), dim3(256), 0, stream>>>(
        x, ei, w1t, w1c, b1, w2t, b2, w2c, wsb, order, hws);
    mixer_out_kernel<false><<<dim3(NBH * 4), dim3(256), 0, stream>>>(
        ei, ew, w2t, w2c, b2, wsb, order2, hws, out);
  }
}

// Round 14
// 165.045 us; speedup vs baseline: 1.4144x; 1.1757x over previous
//
#include <hip/hip_runtime.h>
#include <hip/hip_bf16.h>

// MultiHeadBatchedMixers, group-sorted two-kernel structure (no atomics):
//   prepack+sort: w1t,w2t,x,b1,b2,w1c,w2c -> bf16 ws; block 0 builds order/order2
//   Kernel A (grid 1536x256, XCD-chunked, group-ordered): H = GELU(W1c @ X @ W1t^T + B1)
//       wave owns 64 e: intensity 2 MFMA/load
//   Kernel B (grid 768x256, XCD-chunked, group-ordered): 4 waves = 2 k x 2 wq,
//       wave owns 64 c x 64 n: intensity 2 MFMA/load; LDS combine; plain f32 stores
// bf16 MFMA 16x16x32, f32 accumulate.
// NOTE (R8/R10): VGPR+AGPR share one file on gfx950; never min-waves-bound the
// MFMA kernels (reg cap -> accumulator spill -> WRITE blowup).
// NOTE (R12/R13): cost tracks TOTAL load instructions & MFMA/load intensity, not
// occupancy. Intensity-2 tiles (64x64/wave) beat high-occupancy thin tiles.

namespace {
constexpr int NHEAD = 12, NTOK = 256, HDIM = 64, HIDD = 512, NBATCH = 32, TOPK = 2;
constexpr int NCHAIN = NBATCH * NHEAD * TOPK;  // 768
constexpr int NBH = NBATCH * NHEAD;            // 384
constexpr int NGROUP = 8 * NHEAD;              // 96

// Kernel A LDS: per-wave T1^T [64 e][64 d] bf16, pitch +16B
constexpr int P_T1 = HDIM * 2 + 16;   // 144
constexpr int T1_W = 64 * P_T1;       // 9216
constexpr int SMA_TOTAL = 4 * T1_W;   // 36864
// Kernel B LDS: per-wave T3^T [64 n][64 c] (4 waves); combine aliases [0,32768)
constexpr int P_T3 = HDIM * 2 + 16;   // 144
constexpr int T3_W = 64 * P_T3;       // 9216
constexpr int SMB_TOTAL = 4 * T3_W;   // 36864

// ws layout: [H][w1t][w2t][x][b1][b2][w1c][w2c] bf16, then [order][order2] int
constexpr size_t SZ_H    = (size_t)NCHAIN * HDIM * HIDD;          // 25,165,824
constexpr size_t OFF_H   = 0;
constexpr size_t OFF_W1T = OFF_H + SZ_H;
constexpr size_t SZ_W1T  = (size_t)8 * NHEAD * HIDD * NTOK;       // 12,582,912
constexpr size_t OFF_W2T = OFF_W1T + SZ_W1T;
constexpr size_t SZ_W2T  = (size_t)8 * NHEAD * NTOK * HIDD;
constexpr size_t OFF_X   = OFF_W2T + SZ_W2T;
constexpr size_t SZ_X    = (size_t)NBATCH * NHEAD * HDIM * NTOK;  // 6,291,456
constexpr size_t OFF_B1  = OFF_X + SZ_X;
constexpr size_t SZ_B1   = (size_t)8 * NHEAD * HDIM * HIDD;
constexpr size_t OFF_B2  = OFF_B1 + SZ_B1;
constexpr size_t SZ_B2   = (size_t)8 * NHEAD * HDIM * NTOK;
constexpr size_t OFF_W1C = OFF_B2 + SZ_B2;
constexpr size_t SZ_W1C  = (size_t)8 * NHEAD * HDIM * HDIM;       // 393,216
constexpr size_t OFF_W2C = OFF_W1C + SZ_W1C;
constexpr size_t SZ_W2C  = (size_t)8 * NHEAD * HDIM * HDIM;
constexpr size_t TOTEL   = OFF_W2C + SZ_W2C;                      // shorts
constexpr size_t NEED    = TOTEL * 2 + (NCHAIN + NBH) * 4;
}

typedef float f32x4 __attribute__((ext_vector_type(4)));
typedef short bf16x8 __attribute__((ext_vector_type(8)));
typedef short bf16x4 __attribute__((ext_vector_type(4)));

#define MFMA16(a, b, c) __builtin_amdgcn_mfma_f32_16x16x32_bf16((a), (b), (c), 0, 0, 0)

__device__ __forceinline__ short f2bf(float f) {
  union { float f; unsigned u; } v; v.f = f;
  unsigned r = v.u + 0x7fffu + ((v.u >> 16) & 1u);
  return (short)(r >> 16);
}

__device__ __forceinline__ bf16x8 ld_gfrag(const float* p) {
  float4 a = *(const float4*)p;
  float4 b = *(const float4*)(p + 4);
  bf16x8 r;
  r[0] = f2bf(a.x); r[1] = f2bf(a.y); r[2] = f2bf(a.z); r[3] = f2bf(a.w);
  r[4] = f2bf(b.x); r[5] = f2bf(b.y); r[6] = f2bf(b.z); r[7] = f2bf(b.w);
  return r;
}

__device__ __forceinline__ f32x4 bf4f(bf16x4 v) {
  f32x4 r;
  #pragma unroll
  for (int i = 0; i < 4; ++i) {
    union { unsigned u; float f; } t;
    t.u = ((unsigned)(unsigned short)v[i]) << 16;
    r[i] = t.f;
  }
  return r;
}

__device__ __forceinline__ float gelu_tanh(float x) {
  float u = 0.7978845608028654f * x * (1.0f + 0.044715f * x * x);
  return x / (1.0f + __expf(-2.0f * u));
}

// XCD-chunk swizzle (nwg % 8 == 0): logical sequence contiguous per XCD.
__device__ __forceinline__ int xcd_chunk(int bx, int nwg) {
  return (bx & 7) * (nwg >> 3) + (bx >> 3);
}

// ---------------- Prepack (+ block-0 group sort) ----------------
__global__ __launch_bounds__(256) void prepack_sort_kernel(
    const float* __restrict__ w1t, const float* __restrict__ w2t,
    const float* __restrict__ x, const float* __restrict__ b1,
    const float* __restrict__ b2, const float* __restrict__ w1c,
    const float* __restrict__ w2c, short* __restrict__ wsb,
    const int* __restrict__ eidx, int* __restrict__ order, int* __restrict__ order2) {
  if (blockIdx.x == 0) {
    __shared__ int keys[NCHAIN];
    __shared__ int keys2[NBH];
    __shared__ int cnt[NGROUP + 1];
    __shared__ int cnt2[NGROUP + 1];
    const int t = threadIdx.x;
    for (int i = t; i <= NGROUP; i += 256) { cnt[i] = 0; cnt2[i] = 0; }
    __syncthreads();
    for (int i = t; i < NCHAIN; i += 256) {
      int h = (i >> 1) % NHEAD;
      int key = eidx[i] * NHEAD + h;
      keys[i] = key;
      atomicAdd(&cnt[key + 1], 1);
    }
    for (int i = t; i < NBH; i += 256) {
      int h = i % NHEAD;
      int key = eidx[i * TOPK] * NHEAD + h;
      keys2[i] = key;
      atomicAdd(&cnt2[key + 1], 1);
    }
    __syncthreads();
    if (t == 0) for (int i = 1; i <= NGROUP; ++i) cnt[i] += cnt[i - 1];
    if (t == 1) for (int i = 1; i <= NGROUP; ++i) cnt2[i] += cnt2[i - 1];
    __syncthreads();
    for (int i = t; i < NCHAIN; i += 256) {
      int pos = atomicAdd(&cnt[keys[i]], 1);  // rank within group (order-agnostic downstream)
      order[pos] = i;
    }
    for (int i = t; i < NBH; i += 256) {
      int pos = atomicAdd(&cnt2[keys2[i]], 1);
      order2[pos] = i;
    }
  }

  const size_t C1 = SZ_W1T / 8, C2 = C1 + SZ_W2T / 8, C3 = C2 + SZ_X / 8,
               C4 = C3 + SZ_B1 / 8, C5 = C4 + SZ_B2 / 8, C6 = C5 + SZ_W1C / 8,
               C7 = C6 + SZ_W2C / 8;
  for (size_t i = (size_t)blockIdx.x * blockDim.x + threadIdx.x; i < C7;
       i += (size_t)gridDim.x * blockDim.x) {
    const float* s;
    if (i < C1)      s = w1t + i * 8;
    else if (i < C2) s = w2t + (i - C1) * 8;
    else if (i < C3) s = x   + (i - C2) * 8;
    else if (i < C4) s = b1  + (i - C3) * 8;
    else if (i < C5) s = b2  + (i - C4) * 8;
    else if (i < C6) s = w1c + (i - C5) * 8;
    else             s = w2c + (i - C6) * 8;
    *((bf16x8*)wsb + i) = ld_gfrag(s);  // segments contiguous in ws in same order
  }
}

// ---------------- Kernel A (64 e per wave) ----------------
// grid = 768*2. logical L (XCD-chunked): sid = L>>1 -> chain = order[sid], eblk = L&1.
template <bool PP>
__global__ __launch_bounds__(256) void mixer_h_kernel(
    const float* __restrict__ x, const int* __restrict__ eidx,
    const float* __restrict__ w1t, const float* __restrict__ w1c, const float* __restrict__ b1,
    const short* __restrict__ wsb, const int* __restrict__ order, short* __restrict__ hws) {
  __shared__ __align__(16) char smem[SMA_TOTAL];
  const int L = xcd_chunk(blockIdx.x, NCHAIN * 2);
  const int sid = L >> 1, eblk = L & 1;
  const int bhk = PP ? order[sid] : sid;
  const int h = (bhk >> 1) % NHEAD;
  const int tid = threadIdx.x, w = tid >> 6, lane = tid & 63, lr = lane & 15, lg = lane >> 4;

  const int e = eidx[bhk];
  const size_t eh = (size_t)e * NHEAD + h;
  short* H = hws + (size_t)bhk * HDIM * HIDD;

  const int e0 = eblk * 256 + w * 64;

  // MFMA1: T1[d][e] = sum_n X[d,n]*W1t[e,n];  A=X (m=d), B=W1t (n=e), k=n
  f32x4 acc1[4][4];  // [et][dt]
  #pragma unroll
  for (int et = 0; et < 4; ++et)
    #pragma unroll
    for (int dt = 0; dt < 4; ++dt) acc1[et][dt] = (f32x4){0.f, 0.f, 0.f, 0.f};
  #pragma unroll
  for (int ks = 0; ks < 8; ++ks) {
    bf16x8 wfr[4];
    #pragma unroll
    for (int et = 0; et < 4; ++et) {
      if (PP) wfr[et] = *(const bf16x8*)(wsb + OFF_W1T + eh * HIDD * NTOK +
                                         (size_t)(e0 + et * 16 + lr) * NTOK + ks * 32 + lg * 8);
      else    wfr[et] = ld_gfrag(w1t + eh * HIDD * NTOK +
                                 (size_t)(e0 + et * 16 + lr) * NTOK + ks * 32 + lg * 8);
    }
    #pragma unroll
    for (int dt = 0; dt < 4; ++dt) {
      bf16x8 xfr;
      if (PP) xfr = *(const bf16x8*)(wsb + OFF_X + (size_t)(bhk >> 1) * HDIM * NTOK +
                                     (size_t)(dt * 16 + lr) * NTOK + ks * 32 + lg * 8);
      else    xfr = ld_gfrag(x + (size_t)(bhk >> 1) * HDIM * NTOK +
                             (size_t)(dt * 16 + lr) * NTOK + ks * 32 + lg * 8);
      #pragma unroll
      for (int et = 0; et < 4; ++et) acc1[et][dt] = MFMA16(xfr, wfr[et], acc1[et][dt]);
    }
  }

  // relayout T1^T via wave-private LDS (col=e=lr, row=d=dt*16+lg*4+i) -> [e][d]
  char* t1 = smem + w * T1_W;
  #pragma unroll
  for (int et = 0; et < 4; ++et)
    #pragma unroll
    for (int dt = 0; dt < 4; ++dt) {
      bf16x4 p;
      #pragma unroll
      for (int i = 0; i < 4; ++i) p[i] = f2bf(acc1[et][dt][i]);
      *(bf16x4*)(t1 + (et * 16 + lr) * P_T1 + (dt * 16 + lg * 4) * 2) = p;
    }

  // MFMA2: T2^T[e][c] = sum_d T1^T[e,d]*W1c[c,d] + B1;  D: col=c=lr, row=e=lg*4+i
  f32x4 acc2[4][4];  // [et][ct]
  #pragma unroll
  for (int et = 0; et < 4; ++et)
    #pragma unroll
    for (int ct = 0; ct < 4; ++ct) {
      if (PP) {
        bf16x4 bb = *(const bf16x4*)(wsb + OFF_B1 + eh * HDIM * HIDD +
                                     (size_t)(ct * 16 + lr) * HIDD + e0 + et * 16 + lg * 4);
        acc2[et][ct] = bf4f(bb);
      } else {
        acc2[et][ct] = *(const f32x4*)(b1 + eh * HDIM * HIDD +
                                       (size_t)(ct * 16 + lr) * HIDD + e0 + et * 16 + lg * 4);
      }
    }
  #pragma unroll
  for (int ks = 0; ks < 2; ++ks) {
    bf16x8 a[4];
    #pragma unroll
    for (int et = 0; et < 4; ++et)
      a[et] = *(const bf16x8*)(t1 + (et * 16 + lr) * P_T1 + (ks * 32 + lg * 8) * 2);
    #pragma unroll
    for (int ct = 0; ct < 4; ++ct) {
      bf16x8 bfr;
      if (PP) bfr = *(const bf16x8*)(wsb + OFF_W1C + eh * HDIM * HDIM +
                                     (size_t)(ct * 16 + lr) * HDIM + ks * 32 + lg * 8);
      else    bfr = ld_gfrag(w1c + eh * HDIM * HDIM +
                             (size_t)(ct * 16 + lr) * HDIM + ks * 32 + lg * 8);
      #pragma unroll
      for (int et = 0; et < 4; ++et) acc2[et][ct] = MFMA16(a[et], bfr, acc2[et][ct]);
    }
  }

  // GELU + store H[c][e] (col=c=lr, row=e=lg*4+i)
  #pragma unroll
  for (int et = 0; et < 4; ++et)
    #pragma unroll
    for (int ct = 0; ct < 4; ++ct) {
      bf16x4 g;
      #pragma unroll
      for (int i = 0; i < 4; ++i) g[i] = f2bf(gelu_tanh(acc2[et][ct][i]));
      *(bf16x4*)(H + (size_t)(ct * 16 + lr) * HIDD + e0 + et * 16 + lg * 4) = g;
    }
}

// ---------------- Kernel B v6 (64c x 64n per wave, intensity 2) ----------------
// grid = 768 x 256. L = xcd_chunk(bx, 768): sid = L>>1 -> bh = order2[sid], nhalf = L&1.
// Wave w: kk = w>>1, wq = w&1; n rows [nhalf*128 + wq*64, +64). k=1 waves publish
// weighted partials via LDS (aliases dead t3), k=0 waves combine + plain f32 stores.
template <bool PP>
__global__ __launch_bounds__(256) void mixer_out_kernel(
    const int* __restrict__ eidx, const float* __restrict__ ewt,
    const float* __restrict__ w2t, const float* __restrict__ w2c, const float* __restrict__ b2,
    const short* __restrict__ wsb, const int* __restrict__ order2,
    const short* __restrict__ hws, float* __restrict__ out) {
  __shared__ __align__(16) char smem[SMB_TOTAL];
  const int L = xcd_chunk(blockIdx.x, NBH * 2);
  const int sid = L >> 1, nhalf = L & 1;
  const int bh = PP ? order2[sid] : sid;
  const int h = bh % NHEAD;
  const int tid = threadIdx.x, w = tid >> 6, lane = tid & 63, lr = lane & 15, lg = lane >> 4;
  const int kk = w >> 1, wq = w & 1;
  const int nb = nhalf * 128 + wq * 64;
  char* t3 = smem + w * T3_W;
  float* OUT = out + (size_t)bh * HDIM * NTOK;

  const int e = eidx[bh * TOPK + kk];
  const float wk = ewt[bh * TOPK + kk];
  const size_t eh = (size_t)e * NHEAD + h;
  const short* Hk = hws + (size_t)(bh * TOPK + kk) * HDIM * HIDD;

  // MFMA3: T3[c][n] = sum_e H[c,e]*W2t[n,e];  A=H (m=c), B=W2t (n=n), k=e
  // 16 ks x (4 H-loads + 4 W2T-loads -> 16 MFMA): intensity 2
  f32x4 acc3[4][4];  // [ct][nt]
  #pragma unroll
  for (int ct = 0; ct < 4; ++ct)
    #pragma unroll
    for (int nt = 0; nt < 4; ++nt) acc3[ct][nt] = (f32x4){0.f, 0.f, 0.f, 0.f};
  #pragma unroll 4
  for (int ks = 0; ks < 16; ++ks) {
    bf16x8 a[4];
    #pragma unroll
    for (int ct = 0; ct < 4; ++ct)
      a[ct] = *(const bf16x8*)(Hk + (size_t)(ct * 16 + lr) * HIDD + ks * 32 + lg * 8);
    #pragma unroll
    for (int nt = 0; nt < 4; ++nt) {
      bf16x8 bfr;
      if (PP) bfr = *(const bf16x8*)(wsb + OFF_W2T + eh * NTOK * HIDD +
                                     (size_t)(nb + nt * 16 + lr) * HIDD + ks * 32 + lg * 8);
      else    bfr = ld_gfrag(w2t + eh * NTOK * HIDD +
                             (size_t)(nb + nt * 16 + lr) * HIDD + ks * 32 + lg * 8);
      #pragma unroll
      for (int ct = 0; ct < 4; ++ct) acc3[ct][nt] = MFMA16(a[ct], bfr, acc3[ct][nt]);
    }
  }

  // relayout T3^T via wave-private LDS (col=n=lr, row=c=ct*16+lg*4+i) -> [n][c]
  #pragma unroll
  for (int ct = 0; ct < 4; ++ct)
    #pragma unroll
    for (int nt = 0; nt < 4; ++nt) {
      bf16x4 p;
      #pragma unroll
      for (int i = 0; i < 4; ++i) p[i] = f2bf(acc3[ct][nt][i]);
      *(bf16x4*)(t3 + (nt * 16 + lr) * P_T3 + (ct * 16 + lg * 4) * 2) = p;
    }

  // MFMA4: OUT^T[n][co] = sum_c T3^T[n,c]*W2c[co,c]
  f32x4 acc4[4][4];  // [nt][cot]
  #pragma unroll
  for (int nt = 0; nt < 4; ++nt)
    #pragma unroll
    for (int ct = 0; ct < 4; ++ct) acc4[nt][ct] = (f32x4){0.f, 0.f, 0.f, 0.f};
  #pragma unroll
  for (int ks = 0; ks < 2; ++ks) {
    bf16x8 a[4];
    #pragma unroll
    for (int nt = 0; nt < 4; ++nt)
      a[nt] = *(const bf16x8*)(t3 + (nt * 16 + lr) * P_T3 + (ks * 32 + lg * 8) * 2);
    #pragma unroll
    for (int ct = 0; ct < 4; ++ct) {
      bf16x8 bfr;
      if (PP) bfr = *(const bf16x8*)(wsb + OFF_W2C + eh * HDIM * HDIM +
                                     (size_t)(ct * 16 + lr) * HDIM + ks * 32 + lg * 8);
      else    bfr = ld_gfrag(w2c + eh * HDIM * HDIM +
                             (size_t)(ct * 16 + lr) * HDIM + ks * 32 + lg * 8);
      #pragma unroll
      for (int nt = 0; nt < 4; ++nt) acc4[nt][ct] = MFMA16(a[nt], bfr, acc4[nt][ct]);
    }
  }

  // weighted partial in place: acc4 = wk*(acc4 + B2)  (col=co=lr, row=n=lg*4+i)
  #pragma unroll
  for (int nt = 0; nt < 4; ++nt)
    #pragma unroll
    for (int cot = 0; cot < 4; ++cot) {
      const int co = cot * 16 + lr;
      const int n0 = nb + nt * 16 + lg * 4;
      f32x4 bb;
      if (PP) bb = bf4f(*(const bf16x4*)(wsb + OFF_B2 + eh * HDIM * NTOK + (size_t)co * NTOK + n0));
      else    bb = *(const f32x4*)(b2 + eh * HDIM * NTOK + (size_t)co * NTOK + n0);
      #pragma unroll
      for (int i = 0; i < 4; ++i) acc4[nt][cot][i] = wk * (acc4[nt][cot][i] + bb[i]);
    }

  __syncthreads();  // all waves done reading their t3 (comb aliases t3 region)

  // k=1 waves publish partials: comb[wq] = [64 n][64 co] f32 at offset wq*16384
  if (kk == 1) {
    float* comb = (float*)(smem + wq * 16384);
    #pragma unroll
    for (int nt = 0; nt < 4; ++nt)
      #pragma unroll
      for (int cot = 0; cot < 4; ++cot) {
        const int co = cot * 16 + lr;
        #pragma unroll
        for (int i = 0; i < 4; ++i)
          comb[(nt * 16 + lg * 4 + i) * 64 + co] = acc4[nt][cot][i];
      }
  }
  __syncthreads();

  // k=0 waves combine + store (each (co,n) written exactly once across the grid)
  if (kk == 0) {
    const float* comb = (const float*)(smem + wq * 16384);
    #pragma unroll
    for (int nt = 0; nt < 4; ++nt)
      #pragma unroll
      for (int cot = 0; cot < 4; ++cot) {
        const int co = cot * 16 + lr;
        const int n0 = nb + nt * 16 + lg * 4;
        f32x4 v;
        #pragma unroll
        for (int i = 0; i < 4; ++i)
          v[i] = acc4[nt][cot][i] + comb[(nt * 16 + lg * 4 + i) * 64 + co];
        *(f32x4*)(OUT + (size_t)co * NTOK + n0) = v;
      }
  }
}

extern "C" void kernel_launch(void* const* d_in, const int* in_sizes, int n_in,
                              void* d_out, int out_size, void* d_ws, size_t ws_size,
                              hipStream_t stream) {
  const float* x   = (const float*)d_in[0];
  const int*   ei  = (const int*)d_in[1];
  const float* ew  = (const float*)d_in[2];
  const float* w1t = (const float*)d_in[3];
  const float* w1c = (const float*)d_in[4];
  const float* b1  = (const float*)d_in[5];
  const float* w2t = (const float*)d_in[6];
  const float* w2c = (const float*)d_in[7];
  const float* b2  = (const float*)d_in[8];
  float* out = (float*)d_out;
  short* wsb = (short*)d_ws;
  short* hws = wsb + OFF_H;
  int* order  = (int*)(wsb + TOTEL);
  int* order2 = order + NCHAIN;

  if (ws_size >= NEED) {
    prepack_sort_kernel<<<dim3(2048), dim3(256), 0, stream>>>(
        w1t, w2t, x, b1, b2, w1c, w2c, wsb + OFF_W1T, ei, order, order2);
    mixer_h_kernel<true><<<dim3(NCHAIN * 2), dim3(256), 0, stream>>>(
        x, ei, w1t, w1c, b1, wsb, order, hws);
    mixer_out_kernel<true><<<dim3(NBH * 2), dim3(256), 0, stream>>>(
        ei, ew, w2t, w2c, b2, wsb, order2, hws, out);
  } else {
    mixer_h_kernel<false><<<dim3(NCHAIN * 2), dim3(256), 0, stream>>>(
        x, ei, w1t, w1c, b1, wsb, order, hws);
    mixer_out_kernel<false><<<dim3(NBH * 2), dim3(256), 0, stream>>>(
        ei, ew, w2t, w2c, b2, wsb, order2, hws, out);
  }
}